// Round 7
// baseline (3407.097 us; speedup 1.0000x reference)
//
#include <hip/hip_runtime.h>
#include <math.h>

// 2-layer LSTM (H=512), T=1024 teacher steps + 64 AR steps; only batch row 255
// reaches the output -> single-sequence LSTM. 64 persistent WGs, weights
// register-pinned via opaque asm.
//
// R12: ARRIVAL-COUNTER protocol -- decouple detection from data.
// Evidence: R6 (4x publish transactions -> 2x dur), R11 (flood-rate poll ->
// +110us) show tick time = IC round-trips, contention-inflated by our own
// poll traffic (back-solved RT ~1350cy vs ~450 uncontended). The gen-pair
// protocol structurally forces 64WG x 512thr pollers. Fix:
//  * Data: flat [h1[512] | h2[512]] floats per parity (NO gen tags). Each WG
//    publishes its 16 floats (wave-0 lanes 0..15, relaxed 4B agent stores),
//    then lane 0 does ONE __hip_atomic_fetch_add(cnt,1,RELEASE) -- release
//    drains vmcnt, so data is at IC before the add is visible.
//  * Detection: thread 0 ONLY spins on cnt >= 64*g (64 pollers chip-wide,
//    ~1000x less IC pressure); __syncthreads() broadcasts.
//  * Reads: after the barrier, each lane dwordx4-loads (sc0 sc1, bypass L1/L2
//    -> IC) its own fragments: h1[8sg..8sg+8) and h2[8sg..8sg+8) = exactly
//    c0..c3. NO LDS staging at all. Sound because reads are issued after the
//    counter observation (s_barrier blocks issue) and stores landed at IC
//    before the add (release). R9/R10's torn-read hazard doesn't apply:
//    detection never rides on the data loads.
//  * Slot reuse: WG enters tick g+1 only after all WGs added for g; a WG's
//    add for g follows completion of its tick-g reads (program order) ->
//    overwriting the g-1 parity slot is safe. Monotonic threshold 64*g is
//    exact: max inter-WG skew is 1 tick.
// Counter chain/tick: publish 1RT + add 1RT + detect 1.5RT + read 1RT +
// compute ~750cy at UNCONTENDED RT ~450-500 => ~2900cy vs measured 4230.
//
// Kept from R7 (proven): per-wave gate math (wave rg owns unit U=wg*8+rg of
// both layers), butterfly reduce-scatter, hout LDS handoff + barrier, wave-0
// publish, fast sigf/tanhf. R8 lesson: no LDS spin sync; HW barriers only.

#define G     64      // workgroups
#define NT    512     // threads/wg
#define HD    512     // hidden
#define TT    1024    // teacher steps
#define PRED  64      // prediction length
#define PARF  1024    // floats per parity buffer: [h1[512] | h2[512]]
#define AS    __HIP_MEMORY_SCOPE_AGENT

typedef unsigned long long u64;

#define LOG2E  1.44269504088896340736f

// opaque register pin: makes the asm the producer of the value so the
// compiler cannot rematerialize the original global load inside the loop
#define KEEP4(v) asm volatile("" : "+v"(v.x), "+v"(v.y), "+v"(v.z), "+v"(v.w))

__device__ __forceinline__ float sigf(float x){
  // 1/(1+exp(-x)) via v_exp_f32 + v_rcp_f32 (err ~1e-6, threshold 3.6e-4)
  return __builtin_amdgcn_rcpf(1.0f + __builtin_amdgcn_exp2f(-LOG2E * x));
}
__device__ __forceinline__ float tanhf_fast(float x){
  float e = __builtin_amdgcn_exp2f(2.0f * LOG2E * x);
  return 1.0f - 2.0f * __builtin_amdgcn_rcpf(e + 1.0f);
}
__device__ __forceinline__ float dot4(float4 a, float4 b){
  return a.x*b.x + a.y*b.y + a.z*b.z + a.w*b.w;
}

__global__ __launch_bounds__(NT, 1) void lstm2_kernel(
    const float* __restrict__ input,
    const float* __restrict__ Wih1, const float* __restrict__ Whh1,
    const float* __restrict__ bih1, const float* __restrict__ bhh1,
    const float* __restrict__ Wih2, const float* __restrict__ Whh2,
    const float* __restrict__ bih2, const float* __restrict__ bhh2,
    const float* __restrict__ Wlin, const float* __restrict__ blin,
    float* __restrict__ out, float* __restrict__ ws)
{
  __shared__ __align__(16) float xrow[TT];
  __shared__ float hout[16];    // per-wave gate results: [rg]=h1_U, [8+rg]=h2_U

  float*    comm = ws;                       // [2][PARF] flat h vectors
  unsigned* cnt  = (unsigned*)(ws + 2*PARF); // arrival counter (monotonic)

  const int t  = threadIdx.x;
  const int wg = blockIdx.x;
  const int rg = t >> 6;        // wave id 0..7
  const int sg = t & 63;        // lane
  const int U  = wg*8 + rg;     // hidden unit this wave owns (both layers)

  ((float2*)xrow)[t] = ((const float2*)(input + 255*TT))[t];

  // ---- weight preload: wave owns the 4 gate rows of unit U of both layers.
  // Row for gate q: R = q*HD + U. Lane sg covers cols [8sg, 8sg+8).
  float4 w1[4][2], w2x[4][2], w2h[4][2];
  #pragma unroll
  for (int q=0;q<4;q++){
    const int R = q*HD + U;
    const float* pa = Whh1 + R*HD + sg*8;
    w1[q][0]  = *(const float4*)(pa);
    w1[q][1]  = *(const float4*)(pa+4);
    const float* pb = Wih2 + R*HD + sg*8;
    w2x[q][0] = *(const float4*)(pb);
    w2x[q][1] = *(const float4*)(pb+4);
    const float* pc = Whh2 + R*HD + sg*8;
    w2h[q][0] = *(const float4*)(pc);
    w2h[q][1] = *(const float4*)(pc+4);
  }
  #pragma unroll
  for (int q=0;q<4;q++){
    KEEP4(w1[q][0]);  KEEP4(w1[q][1]);
    KEEP4(w2x[q][0]); KEEP4(w2x[q][1]);
    KEEP4(w2h[q][0]); KEEP4(w2h[q][1]);
  }

  // lane 0 computes L1 unit U, lane 1 computes L2 unit U
  float bias[4]={0,0,0,0}, wx[4]={0,0,0,0};
  if (sg < 2){
    const float* bi = sg ? bih2 : bih1;
    const float* bh = sg ? bhh2 : bhh1;
    #pragma unroll
    for (int q=0;q<4;q++){
      const int R = q*HD + U;
      bias[q] = bi[R] + bh[R];
      if (sg == 0) wx[q] = Wih1[R];
    }
  }
  float4 wl0 = *(const float4*)(Wlin + sg*8);
  float4 wl1 = *(const float4*)(Wlin + sg*8 + 4);
  const float blin0 = blin[0];

  float cst  = 0.f;     // persistent cell state (lane 0: c1_U, lane 1: c2_U)
  float hcur = 0.f;     // last h this lane produced (re-published every tick)

  // ---- detect tick g ready: thread 0 spins on the arrival counter, barrier
  // broadcasts. g=0: threshold 0, no spin (memset zeros = initial state).
  auto detect = [&](unsigned g){
    if (t == 0){
      const unsigned want = g * 64u;
      while (__hip_atomic_load(cnt, __ATOMIC_RELAXED, AS) < want) {}
    }
    __syncthreads();
  };

  // ---- fragment read: lane sg's c0..c3 straight from IC (sc0 sc1 bypass).
  // One asm block: 4 loads in flight, single vmcnt drain; "=&v" early-clobber
  // (R9 lesson) so outputs never alias the address pairs.
  auto load_frags = [&](unsigned g, float4& c0, float4& c1, float4& c2, float4& c3){
    const float* pc = comm + (g & 1u)*PARF;
    const u64 a0 = (u64)(pc + 8*sg);
    const u64 a1 = (u64)(pc + 8*sg + 4);
    const u64 a2 = (u64)(pc + 512 + 8*sg);
    const u64 a3 = (u64)(pc + 512 + 8*sg + 4);
    asm volatile(
      "global_load_dwordx4 %0, %4, off sc0 sc1\n\t"
      "global_load_dwordx4 %1, %5, off sc0 sc1\n\t"
      "global_load_dwordx4 %2, %6, off sc0 sc1\n\t"
      "global_load_dwordx4 %3, %7, off sc0 sc1\n\t"
      "s_waitcnt vmcnt(0)"
      : "=&v"(c0), "=&v"(c1), "=&v"(c2), "=&v"(c3)
      : "v"(a0), "v"(a1), "v"(a2), "v"(a3)
      : "memory");
  };

  // ---- one tick: per-wave dots + butterfly + lane-0/1 gate math -> hout
  // handoff barrier -> wave 0 publishes 16 floats + ONE release add.
  auto tick = [&](unsigned g, bool d1, bool d2, float xv){
    float4 c0, c1, c2, c3;
    load_frags(g, c0, c1, c2, c3);
    float v[8];   // v[0..3]=gates i,f,g,o of L1 unit U; v[4..7]=L2 unit U
    #pragma unroll
    for (int k=0;k<4;k++){
      v[k]   = dot4(w1[k][0],c0) + dot4(w1[k][1],c1);
      v[4+k] = dot4(w2x[k][0],c0) + dot4(w2x[k][1],c1)
             + dot4(w2h[k][0],c2) + dot4(w2h[k][1],c3);
    }
    // butterfly reduce-scatter: afterwards lane(j)=bitrev3(j) holds sum v[j]
    const int b0 = sg & 1, b1 = (sg>>1)&1, b2 = (sg>>2)&1;
    float k4[4];
    #pragma unroll
    for (int k=0;k<4;k++){
      float x = b0 ? v[k] : v[k+4];
      float y = __shfl_xor(x, 1, 64);
      k4[k] = (b0 ? v[k+4] : v[k]) + y;
    }
    float k2[2];
    #pragma unroll
    for (int k=0;k<2;k++){
      float x = b1 ? k4[k] : k4[k+2];
      float y = __shfl_xor(x, 2, 64);
      k2[k] = (b1 ? k4[k+2] : k4[k]) + y;
    }
    float k1;
    {
      float x = b2 ? k2[0] : k2[1];
      float y = __shfl_xor(x, 4, 64);
      k1 = (b2 ? k2[1] : k2[0]) + y;
    }
    k1 += __shfl_xor(k1, 8, 64);
    k1 += __shfl_xor(k1, 16, 64);
    k1 += __shfl_xor(k1, 32, 64);
    // gather gates of unit U for lane p (p=0: L1, p=1: L2).
    // value j lives at lane bitrev3(j): i->lane p, f->4+p, g->2+p, o->6+p.
    const int p = sg & 1;
    float pi = __shfl(k1, p,     64);
    float pf = __shfl(k1, 4 + p, 64);
    float pg = __shfl(k1, 2 + p, 64);
    float po = __shfl(k1, 6 + p, 64);
    const float xb = p ? 0.f : xv;
    pi += xb*wx[0] + bias[0];
    pf += xb*wx[1] + bias[1];
    pg += xb*wx[2] + bias[2];
    po += xb*wx[3] + bias[3];
    const bool act = p ? d2 : d1;       // lanes >=2 compute garbage, never read
    float cn = sigf(pf)*cst + sigf(pi)*tanhf_fast(pg);
    float hn = sigf(po)*tanhf_fast(cn);
    if (act){ cst = cn; hcur = hn; }
    if (sg < 2) hout[rg + 8*p] = hcur;    // [rg]=h1_U, [8+rg]=h2_U
    __syncthreads();                      // handoff barrier
    if (t < 16){
      // flat publish: t<8 -> h1[wg*8+t], t>=8 -> h2 at [512 + wg*8 + (t-8)]
      float* nb = comm + ((g+1u) & 1u)*PARF
                + ((t < 8) ? (wg*8 + t) : (512 + wg*8 + (t-8)));
      __hip_atomic_store(nb, hout[t], __ATOMIC_RELAXED, AS);
    }
    if (t == 0){
      // RELEASE: drains vmcnt -> the 16 data stores are at IC before the
      // counter increment becomes visible.
      __hip_atomic_fetch_add(cnt, 1u, __ATOMIC_RELEASE, AS);
    }
  };

  // o = Wlin . h2 + blin, fragments straight from IC; result in ALL lanes
  auto computeO = [&](unsigned g)->float{
    const float* pc = comm + (g & 1u)*PARF;
    const u64 a2 = (u64)(pc + 512 + 8*sg);
    const u64 a3 = (u64)(pc + 512 + 8*sg + 4);
    float4 c2, c3;
    asm volatile(
      "global_load_dwordx4 %0, %2, off sc0 sc1\n\t"
      "global_load_dwordx4 %1, %3, off sc0 sc1\n\t"
      "s_waitcnt vmcnt(0)"
      : "=&v"(c2), "=&v"(c3)
      : "v"(a2), "v"(a3)
      : "memory");
    float s = dot4(wl0, c2) + dot4(wl1, c3);
    #pragma unroll
    for (int m=1;m<64;m<<=1) s += __shfl_xor(s, m, 64);
    return s + blin0;
  };

  __syncthreads();   // xrow staged

  unsigned g = 0;

  // ---- teacher: tick g computes L1 step g || L2 step g-1 ----
  for (int tk=0; tk<TT; ++tk, ++g){
    detect(g);                           // parity g&1 = [h1_{g-1} | h2_{g-2}]
    tick(g, true, tk >= 1, xrow[tk]);    // publish [h1_g | h2_{g-1}] + add
  }

  // ---- drain: L2 step 1023 ----
  detect(g);                             // [h1_1023 | h2_1022]
  tick(g, false, true, 0.f);             // publish [h1_1023 | h2_1023]
  ++g;

  // ---- AR: steps s = 1024..1086, 2 ticks each ----
  for (int s=TT; s<TT+PRED-1; ++s){
    detect(g);                           // [h1_{s-1} | h2_{s-1}]
    float xv = computeO(g);              // o_{s-1}, all waves redundantly
    if (wg == 0 && t == 0) out[s - TT] = xv;
    tick(g, true, false, xv);            // publish [h1_s | h2_{s-1}]
    ++g;

    detect(g);                           // [h1_s | h2_{s-1}]
    tick(g, false, true, 0.f);           // publish [h1_s | h2_s]
    ++g;
  }

  // ---- final output o_1086 ----
  detect(g);                             // [h1_1086 | h2_1086]
  float xv = computeO(g);
  if (wg == 0 && t == 0) out[PRED - 1] = xv;
}

extern "C" void kernel_launch(void* const* d_in, const int* in_sizes, int n_in,
                              void* d_out, int out_size, void* d_ws, size_t ws_size,
                              hipStream_t stream) {
  const float* input = (const float*)d_in[0];
  // d_in[1] = pred_len (fixed 64, baked in)
  const float* Wih1 = (const float*)d_in[2];
  const float* Whh1 = (const float*)d_in[3];
  const float* bih1 = (const float*)d_in[4];
  const float* bhh1 = (const float*)d_in[5];
  const float* Wih2 = (const float*)d_in[6];
  const float* Whh2 = (const float*)d_in[7];
  const float* bih2 = (const float*)d_in[8];
  const float* bhh2 = (const float*)d_in[9];
  const float* Wlin = (const float*)d_in[10];
  const float* blin = (const float*)d_in[11];

  // zero comm (h=0 initial state, both parities) + arrival counter
  hipMemsetAsync(d_ws, 0, (2*PARF + 4) * sizeof(float), stream);

  lstm2_kernel<<<dim3(G), dim3(NT), 0, stream>>>(
      input, Wih1, Whh1, bih1, bhh1, Wih2, Whh2, bih2, bhh2, Wlin, blin,
      (float*)d_out, (float*)d_ws);
}

// Round 9
// 2071.577 us; speedup vs baseline: 1.6447x; 1.6447x over previous
//
#include <hip/hip_runtime.h>
#include <math.h>

// 2-layer LSTM (H=512), T=1024 teacher steps + 64 AR steps; only batch row 255
// reaches the output -> single-sequence LSTM. 64 persistent WGs, weights
// register-pinned via opaque asm.
//
// R14 = R7 (proven base) + MANTISSA-TAGGED PAIRS: a comm pair is now TWO h
// floats (h_even's low 3 mantissa bits replaced by g&7, h_odd clean) instead
// of (gen<<32 | h). The 8B atomic load still fuses detection+data in one IC
// round trip (R12 proved decoupling is -1300us), but now carries 2 h values:
//  * poll loads halve chip-wide (each thread polls ONE pair, not two)
//  * publish halves: 8 lanes x 8B = one 64B coalesced burst (single
//    transaction -- R6's scattered-multi-wave failure mode doesn't apply)
//  * line stride padded to 512B -> per-IC-sector poll pressure halves too
// Numerics: tag perturbs h_even by <= 8 ulp (~5e-7 rel); forget-gate
// contraction keeps accumulation ~1e-6 << 3.6e-4 threshold.
// Tag soundness: during tick-g poll a slot holds gen g-2 or g (same causality
// as R5/R7); (g-2)&7 != g&7 always; 8B atomicity forbids torn pairs (R9/R10:
// non-atomic wide loads over pairs tear -> absmax 1e-2, twice-paid lesson).
//
// Kept bit-identical from R7 (lessons R6/R8/R11/R12/R13):
//  - fused detect+data atomic poll, unpipelined (R11: flood poll +110us)
//  - single coalesced wave-0 publish after the handoff barrier
//  - HW barriers for intra-WG sync (R8: LDS flag/spin sync +290us)
//  - per-wave gate math before the barrier (R7), butterfly reduce-scatter
//  - agent-scope comm (R13 XCD-local experiment hung; abandoned)
// hvec chunk stride padded 256->264 words (4-way staging conflicts otherwise).

#define G     64      // workgroups
#define NT    512     // threads/wg
#define HD    512     // hidden
#define TT    1024    // teacher steps
#define PRED  64      // prediction length
#define LINEF 128     // floats per comm line slot (512 B); pairs in words 0..15
#define SLOTF (G*LINEF)
#define STR   264     // hvec chunk stride in words (256 data + 8 pad banks)
#define AS    __HIP_MEMORY_SCOPE_AGENT

typedef unsigned long long u64;

#define LOG2E  1.44269504088896340736f

// opaque register pin: makes the asm the producer of the value so the
// compiler cannot rematerialize the original global load inside the loop
#define KEEP4(v) asm volatile("" : "+v"(v.x), "+v"(v.y), "+v"(v.z), "+v"(v.w))

__device__ __forceinline__ float sigf(float x){
  // 1/(1+exp(-x)) via v_exp_f32 + v_rcp_f32 (err ~1e-6, threshold 3.6e-4)
  return __builtin_amdgcn_rcpf(1.0f + __builtin_amdgcn_exp2f(-LOG2E * x));
}
__device__ __forceinline__ float tanhf_fast(float x){
  float e = __builtin_amdgcn_exp2f(2.0f * LOG2E * x);
  return 1.0f - 2.0f * __builtin_amdgcn_rcpf(e + 1.0f);
}
__device__ __forceinline__ float dot4(float4 a, float4 b){
  return a.x*b.x + a.y*b.y + a.z*b.z + a.w*b.w;
}

__global__ __launch_bounds__(NT, 1) void lstm2_kernel(
    const float* __restrict__ input,
    const float* __restrict__ Wih1, const float* __restrict__ Whh1,
    const float* __restrict__ bih1, const float* __restrict__ bhh1,
    const float* __restrict__ Wih2, const float* __restrict__ Whh2,
    const float* __restrict__ bih2, const float* __restrict__ bhh2,
    const float* __restrict__ Wlin, const float* __restrict__ blin,
    float* __restrict__ out, float* __restrict__ ws)
{
  // hvec chunk c (c=0..3) = words [c*STR, c*STR+256):
  //   c0: h1 units {8w..8w+3} of line w at word 4w   c1: h1 units {8w+4..8w+7}
  //   c2: h2 units {8w..8w+3}                        c3: h2 units {8w+4..8w+7}
  __shared__ __align__(16) float hvec[4*STR];
  __shared__ __align__(16) float xrow[TT];
  __shared__ float hout[16];    // per-wave gate results: [rg]=h1_U, [8+rg]=h2_U

  float* comm = ws;             // [2][G][LINEF]

  const int t  = threadIdx.x;
  const int wg = blockIdx.x;
  const int rg = t >> 6;        // wave id 0..7
  const int sg = t & 63;        // lane
  const int U  = wg*8 + rg;     // hidden unit this wave owns (both layers)

  ((float2*)xrow)[t] = ((const float2*)(input + 255*TT))[t];

  // ---- weight preload: wave owns the 4 gate rows of unit U of both layers.
  // Row for gate q: R = q*HD + U. Lane sg covers cols [8sg, 8sg+8).
  float4 w1[4][2], w2x[4][2], w2h[4][2];
  #pragma unroll
  for (int q=0;q<4;q++){
    const int R = q*HD + U;
    const float* pa = Whh1 + R*HD + sg*8;
    w1[q][0]  = *(const float4*)(pa);
    w1[q][1]  = *(const float4*)(pa+4);
    const float* pb = Wih2 + R*HD + sg*8;
    w2x[q][0] = *(const float4*)(pb);
    w2x[q][1] = *(const float4*)(pb+4);
    const float* pc = Whh2 + R*HD + sg*8;
    w2h[q][0] = *(const float4*)(pc);
    w2h[q][1] = *(const float4*)(pc+4);
  }
  #pragma unroll
  for (int q=0;q<4;q++){
    KEEP4(w1[q][0]);  KEEP4(w1[q][1]);
    KEEP4(w2x[q][0]); KEEP4(w2x[q][1]);
    KEEP4(w2h[q][0]); KEEP4(w2h[q][1]);
  }

  // lane 0 computes L1 unit U, lane 1 computes L2 unit U
  float bias[4]={0,0,0,0}, wx[4]={0,0,0,0};
  if (sg < 2){
    const float* bi = sg ? bih2 : bih1;
    const float* bh = sg ? bhh2 : bhh1;
    #pragma unroll
    for (int q=0;q<4;q++){
      const int R = q*HD + U;
      bias[q] = bi[R] + bh[R];
      if (sg == 0) wx[q] = Wih1[R];
    }
  }
  float4 wl0 = *(const float4*)(Wlin + sg*8);
  float4 wl1 = *(const float4*)(Wlin + sg*8 + 4);
  const float blin0 = blin[0];

  float cst  = 0.f;     // persistent cell state (lane 0: c1_U, lane 1: c2_U)
  float hcur = 0.f;     // last h this lane produced (re-published every tick)

  // ---- consume tick g: all 512 threads. Thread t polls pair i=t&7 of line
  // w=t>>3 (ONE 8B atomic load: h_{2i} tagged in low word, h_{2i+1} in high).
  // Spin until tag == g&7 -> detection and 2 h values in ONE IC round trip.
  auto poll_stage = [&](unsigned g){
    const int w = t >> 3, i = t & 7;
    const u64* dq = (const u64*)(comm + (g & 1u)*SLOTF + w*LINEF) + i;
    const unsigned tag = g & 7u;
    u64 q;
    do {
      q = __hip_atomic_load(dq, __ATOMIC_RELAXED, AS);
    } while (((unsigned)q & 7u) != tag);
    const int c  = i >> 1;
    const int wd = c*STR + 4*w + 2*(i & 1);
    float2 fv;
    fv.x = __builtin_bit_cast(float, (unsigned)q);          // h_even (tagged)
    fv.y = __builtin_bit_cast(float, (unsigned)(q >> 32));  // h_odd
    *(float2*)(hvec + wd) = fv;
    __syncthreads();
  };

  // ---- one tick: per-wave dots + butterfly + lane-0/1 gate math (parallel
  // across waves, BEFORE the barrier) -> LDS handoff -> wave 0 publishes the
  // whole line as one coalesced 64B burst (8 lanes x 8B pairs).
  auto tick = [&](unsigned g, bool d1, bool d2, float xv){
    const float4 c0 = ((const float4*)(hvec + 0*STR))[sg];
    const float4 c1 = ((const float4*)(hvec + 1*STR))[sg];
    const float4 c2 = ((const float4*)(hvec + 2*STR))[sg];
    const float4 c3 = ((const float4*)(hvec + 3*STR))[sg];
    float v[8];   // v[0..3]=gates i,f,g,o of L1 unit U; v[4..7]=L2 unit U
    #pragma unroll
    for (int k=0;k<4;k++){
      v[k]   = dot4(w1[k][0],c0) + dot4(w1[k][1],c1);
      v[4+k] = dot4(w2x[k][0],c0) + dot4(w2x[k][1],c1)
             + dot4(w2h[k][0],c2) + dot4(w2h[k][1],c3);
    }
    // butterfly reduce-scatter: afterwards lane(j)=bitrev3(j) holds sum v[j]
    const int b0 = sg & 1, b1 = (sg>>1)&1, b2 = (sg>>2)&1;
    float k4[4];
    #pragma unroll
    for (int k=0;k<4;k++){
      float x = b0 ? v[k] : v[k+4];
      float y = __shfl_xor(x, 1, 64);
      k4[k] = (b0 ? v[k+4] : v[k]) + y;
    }
    float k2[2];
    #pragma unroll
    for (int k=0;k<2;k++){
      float x = b1 ? k4[k] : k4[k+2];
      float y = __shfl_xor(x, 2, 64);
      k2[k] = (b1 ? k4[k+2] : k4[k]) + y;
    }
    float k1;
    {
      float x = b2 ? k2[0] : k2[1];
      float y = __shfl_xor(x, 4, 64);
      k1 = (b2 ? k2[1] : k2[0]) + y;
    }
    k1 += __shfl_xor(k1, 8, 64);
    k1 += __shfl_xor(k1, 16, 64);
    k1 += __shfl_xor(k1, 32, 64);
    // gather gates of unit U for lane p (p=0: L1, p=1: L2).
    // value j lives at lane bitrev3(j): i->lane p, f->4+p, g->2+p, o->6+p.
    const int p = sg & 1;
    float pi = __shfl(k1, p,     64);
    float pf = __shfl(k1, 4 + p, 64);
    float pg = __shfl(k1, 2 + p, 64);
    float po = __shfl(k1, 6 + p, 64);
    const float xb = p ? 0.f : xv;
    pi += xb*wx[0] + bias[0];
    pf += xb*wx[1] + bias[1];
    pg += xb*wx[2] + bias[2];
    po += xb*wx[3] + bias[3];
    const bool act = p ? d2 : d1;       // lanes >=2 compute garbage, never read
    float cn = sigf(pf)*cst + sigf(pi)*tanhf_fast(pg);
    float hn = sigf(po)*tanhf_fast(cn);
    if (act){ cst = cn; hcur = hn; }
    if (sg < 2) hout[rg + 8*p] = hcur;    // [rg]=h1_U, [8+rg]=h2_U
    __syncthreads();                      // barrier 2: handoff + hvec-reuse
    if (t < 8){
      // pair t = (h[2t] with low-3 mantissa bits = (g+1)&7, h[2t+1] clean)
      unsigned he = __builtin_bit_cast(unsigned, hout[2*t]);
      he = (he & ~7u) | ((g + 1u) & 7u);
      u64 pr = (u64)he
             | ((u64)__builtin_bit_cast(unsigned, hout[2*t + 1]) << 32);
      u64* nb = (u64*)(comm + ((g+1u) & 1u)*SLOTF + wg*LINEF);
      __hip_atomic_store(nb + t, pr, __ATOMIC_RELAXED, AS);
    }
  };

  // o = Wlin . h2 + blin from hvec chunks 2/3; per-wave, result in ALL lanes
  auto computeO = [&](){
    float s = dot4(wl0, ((const float4*)(hvec + 2*STR))[sg])
            + dot4(wl1, ((const float4*)(hvec + 3*STR))[sg]);
    #pragma unroll
    for (int m=1;m<64;m<<=1) s += __shfl_xor(s, m, 64);
    return s + blin0;
  };

  __syncthreads();   // xrow staged

  unsigned g = 0;

  // ---- teacher: tick g computes L1 step g || L2 step g-1 ----
  for (int tk=0; tk<TT; ++tk, ++g){
    poll_stage(g);                       // hvec = [h1_{g-1} | h2_{g-2}]
    tick(g, true, tk >= 1, xrow[tk]);    // publish [h1_g | h2_{g-1}] pairs
  }

  // ---- drain: L2 step 1023 ----
  poll_stage(g);                         // [h1_1023 | h2_1022]
  tick(g, false, true, 0.f);             // publish [h1_1023 | h2_1023]
  ++g;

  // ---- AR: steps s = 1024..1086, 2 ticks each ----
  for (int s=TT; s<TT+PRED-1; ++s){
    poll_stage(g);                       // [h1_{s-1} | h2_{s-1}]
    float xv = computeO();               // o_{s-1}, all waves redundantly
    if (wg == 0 && t == 0) out[s - TT] = xv;
    tick(g, true, false, xv);            // publish [h1_s | h2_{s-1}]
    ++g;

    poll_stage(g);                       // [h1_s | h2_{s-1}]
    tick(g, false, true, 0.f);           // publish [h1_s | h2_s]
    ++g;
  }

  // ---- final output o_1086 ----
  poll_stage(g);                         // [h1_1086 | h2_1086]
  float xv = computeO();
  if (wg == 0 && t == 0) out[PRED - 1] = xv;
}

extern "C" void kernel_launch(void* const* d_in, const int* in_sizes, int n_in,
                              void* d_out, int out_size, void* d_ws, size_t ws_size,
                              hipStream_t stream) {
  const float* input = (const float*)d_in[0];
  // d_in[1] = pred_len (fixed 64, baked in)
  const float* Wih1 = (const float*)d_in[2];
  const float* Whh1 = (const float*)d_in[3];
  const float* bih1 = (const float*)d_in[4];
  const float* bhh1 = (const float*)d_in[5];
  const float* Wih2 = (const float*)d_in[6];
  const float* Whh2 = (const float*)d_in[7];
  const float* bih2 = (const float*)d_in[8];
  const float* bhh2 = (const float*)d_in[9];
  const float* Wlin = (const float*)d_in[10];
  const float* blin = (const float*)d_in[11];

  // zero comm: zero pairs == (tag 0 == gen 0 mod 8, h=0.0f) -> valid initial
  hipMemsetAsync(d_ws, 0, 2 * SLOTF * sizeof(float), stream);

  lstm2_kernel<<<dim3(G), dim3(NT), 0, stream>>>(
      input, Wih1, Whh1, bih1, bhh1, Wih2, Whh2, bih2, bhh2, Wlin, blin,
      (float*)d_out, (float*)d_ws);
}